// Round 17
// baseline (1301.517 us; speedup 1.0000x reference)
//
#include <hip/hip_runtime.h>
#include <hip/hip_fp16.h>
#include <math.h>

#define N_IMG  512
#define N_Z    8
#define N_VIEW 360
#define N_DET  512
#define N_S    512
#define SLICE  (N_IMG * N_IMG)

// Padded fp16 row-pair x z-pair volume in ws (8B cells):
//   PV2[zp][r][c].x = half2( P_{2zp}  (r-2, c-2), P_{2zp}  (r-1, c-2) )
//   PV2[zp][r][c].y = half2( P_{2zp+1}(r-2, c-2), P_{2zp+1}(r-1, c-2) )
// P = vol zero-padded. r in [0,514] covers row civ in [-2,512]; c covers ciu in [-2,513].
#define PV_ROWS    515
#define PV_PITCH   516
#define PV_ZSTRIDE (PV_ROWS * PV_PITCH)   // uint2 cells
#define NV 4          // views per block
#define DG 16         // detectors per block (512thr: window sharing via 2 det-halves)
#define SC 32         // s samples per chunk
#define NCHUNK (N_S / SC)
#define STC  64       // cells per LDS row (power of 2 -> XOR swizzle legal)
#define ROWS 52       // window rows (exact-union span proven <= 50)
#define BUFC (ROWS * STC)   // 3328 cells = 26 slots x 128
#define NSLOT 26      // 16B-seg slots per window (52 rows x 32 segs / 64 lanes)
#define NDMA 4        // max dma16 per thread per window
// Swizzle: LDS cell (r, k) holds pv col u0p2 + (k ^ XRC(r)). DMA source is
// pre-swizzled (XRC multiple of 4 cells -> 16B (2-cell) segments contiguous &
// aligned); reads use k = ku ^ XRC(row). Rule-21 compliant.
#define XRC(r) (((r) & 7) << 2)

typedef _Float16 half2v __attribute__((ext_vector_type(2)));
typedef __fp16   fp16x2 __attribute__((ext_vector_type(2)));

__device__ __forceinline__ half2v pkrtz(float a, float b) {
    return __builtin_bit_cast(half2v, __builtin_amdgcn_cvt_pkrtz(a, b));
}

__device__ __forceinline__ void dma16(const unsigned* g, unsigned* l) {
    // async global->LDS, 16B/lane; LDS dest = wave-uniform base + lane*16
    __builtin_amdgcn_global_load_lds((const __attribute__((address_space(1))) unsigned*)g,
                                     (__attribute__((address_space(3))) unsigned*)l,
                                     16, 0, 0);
}

__global__ __launch_bounds__(256) void pad_kernel(const float* __restrict__ vol,
                                                  uint2* __restrict__ pv) {
    const int zr = blockIdx.x;                  // 0 .. 4*PV_ROWS-1
    const int zp = zr / PV_ROWS;
    const int r  = zr - zp * PV_ROWS;
    const float* __restrict__ i0 = vol + (size_t)(2 * zp) * SLICE;
    const float* __restrict__ i1 = i0 + SLICE;
    uint2* __restrict__ dst = pv + (size_t)zp * PV_ZSTRIDE + (size_t)r * PV_PITCH;
    const int y0 = r - 2, y1 = r - 1;
    const bool y0ok = (unsigned)y0 < (unsigned)N_IMG;
    const bool y1ok = (unsigned)y1 < (unsigned)N_IMG;
    for (int c = threadIdx.x; c < PV_PITCH; c += 256) {
        const int x = c - 2;
        const bool xok = (unsigned)x < (unsigned)N_IMG;
        const float e0 = (y0ok && xok) ? i0[y0 * N_IMG + x] : 0.0f;
        const float e1 = (y1ok && xok) ? i0[y1 * N_IMG + x] : 0.0f;
        const float o0 = (y0ok && xok) ? i1[y0 * N_IMG + x] : 0.0f;
        const float o1 = (y1ok && xok) ? i1[y1 * N_IMG + x] : 0.0f;
        __half2 he; he.x = __float2half(e0); he.y = __float2half(e1);
        __half2 ho; ho.x = __float2half(o0); ho.y = __float2half(o1);
        uint2 cell;
        cell.x = *reinterpret_cast<unsigned*>(&he);
        cell.y = *reinterpret_cast<unsigned*>(&ho);
        dst[c] = cell;
    }
}

// Stage one zp window (52 rows x 32 segs = 26 slots). Slot predicate is
// wave-uniform (no partial slots: 26*64 = 1664 segs exactly).
#define DMA_WINDOW(ZP, B)                                                     \
    {                                                                         \
        const uint2* __restrict__ pvz = pv + (size_t)(ZP) * PV_ZSTRIDE;       \
        _Pragma("unroll")                                                     \
        for (int i = 0; i < NDMA; i++) {                                      \
            if (wvid * NDMA + i < NSLOT) {                                    \
                const int rowg = min(v0p2 + dmarow[i], PV_ROWS - 1);          \
                dma16((const unsigned*)(pvz + (size_t)rowg * PV_PITCH         \
                                        + (u0p2 + dmascol[i])),               \
                      (unsigned*)&sm2[B][(wvid * NDMA + i) * 128]);           \
            }                                                                 \
        }                                                                     \
    }

// Per-wave counted wait: window N-1 complete iff outstanding <= own issue
// count for window N ({4,4,4,4,4,4,2,0} per wave) — wave-uniform branch.
#define WAIT_PREV()                                                           \
    {                                                                         \
        if (wvid < 6)       asm volatile("s_waitcnt vmcnt(4)" ::: "memory");  \
        else if (wvid == 6) asm volatile("s_waitcnt vmcnt(2)" ::: "memory");  \
        else                asm volatile("s_waitcnt vmcnt(0)" ::: "memory");  \
    }

// One sample: 2x ds_read_b64 serve the bilinear for BOTH z of the pair.
#define GATHER(ZP, B)                                                         \
    {                                                                         \
        _Pragma("unroll")                                                     \
        for (int ks = 0; ks < 4; ks++) {                                      \
            const uint2 q0 = sm2[B][offs0[ks]];                               \
            const uint2 q1 = sm2[B][offs1[ks]];                               \
            const half2v w0 = w0a[ks], w1 = w1a[ks];                          \
            acc[2*(ZP)]   = __builtin_amdgcn_fdot2(                           \
                __builtin_bit_cast(half2v, q1.x), w1,                         \
                __builtin_amdgcn_fdot2(__builtin_bit_cast(half2v, q0.x),      \
                                       w0, acc[2*(ZP)], false),               \
                false);                                                       \
            acc[2*(ZP)+1] = __builtin_amdgcn_fdot2(                           \
                __builtin_bit_cast(half2v, q1.y), w1,                         \
                __builtin_amdgcn_fdot2(__builtin_bit_cast(half2v, q0.y),      \
                                       w0, acc[2*(ZP)+1], false),             \
                false);                                                       \
        }                                                                     \
    }

// Block: 512 threads = 8 waves = 4 views x 2 det-halves; 16 dets; all 8 z.
// Window 52x64 cells -> 53.2KB dbuf -> 3 blocks/CU = 24 waves (75% cap),
// vs R15's 2 blocks/16 waves. Lane = 8 dets x 8 s-phases; ND=1.
// launch_bounds(512,6): VGPR cap 85 (need ~60; ND=1 state is half of R15's 64).
__global__ __launch_bounds__(512, 6) void proj_kernel(const uint2* __restrict__ pv,
                                                      float* __restrict__ out) {
    __shared__ __align__(16) uint2 sm2[2][BUFC];

    const int g     = blockIdx.x >> 5;         // view group 0..89
    const int dg    = blockIdx.x & 31;         // det group 0..31
    const int tid   = threadIdx.x;
    const int wvid  = tid >> 6;                // wave 0..7
    const int viewt = wvid >> 1;               // wave -> view
    const int deth  = wvid & 1;                // det half 0/1
    const int lane  = tid & 63;
    const int kp    = lane & 7;                // s-phase (also the output z)
    const int tl    = lane >> 3;               // det-lane 0..7
    const int view  = g * NV + viewt;

    // Per-thread DMA geometry: seg -> (row, pre-swizzled source col).
    int dmarow[NDMA], dmascol[NDMA];
    #pragma unroll
    for (int i = 0; i < NDMA; i++) {
        const int seg = (wvid * NDMA + i) * 64 + lane;   // 0..2047 (1664 used)
        const int r   = seg >> 5;                        // 32 segs/row
        dmarow[i]  = r;
        dmascol[i] = ((seg & 31) * 2) ^ XRC(r);          // 2 cells per 16B seg
    }

    const float KTH = (float)(M_PI / 360.0);
    float c0, s0, c1, s1, c2, s2, c3, s3;
    sincosf((float)(g * 4 + 0) * KTH, &s0, &c0);
    sincosf((float)(g * 4 + 1) * KTH, &s1, &c1);
    sincosf((float)(g * 4 + 2) * KTH, &s2, &c2);
    sincosf((float)(g * 4 + 3) * KTH, &s3, &c3);
    const float c_my = (viewt == 0) ? c0 : (viewt == 1) ? c1 : (viewt == 2) ? c2 : c3;
    const float s_my = (viewt == 0) ? s0 : (viewt == 1) ? s1 : (viewt == 2) ? s2 : s3;

    const float t_base = (float)(dg * DG) - 255.5f;
    const float tt  = t_base + (float)(deth * 8 + tl);
    const float buv = fmaf(-s_my, tt, 255.5f);     // u = c*s + buv
    const float bvv = fmaf( c_my, tt, 255.5f);     // v = si*s + bvv

    float acc[N_Z];
    #pragma unroll
    for (int zz = 0; zz < N_Z; zz++) acc[zz] = 0.0f;

    for (int ck = 0; ck < NCHUNK; ++ck) {
        const float sA = (float)(ck * SC) - 255.5f;
        const float sB = sA + (float)(SC - 1);
        const float tA = t_base, tB = t_base + (float)(DG - 1);

        // Union bbox over the 4 views (block-uniform, separable corner min/max).
        float umin = 1e30f, umax = -1e30f, vmin = 1e30f, vmax = -1e30f;
        #pragma unroll
        for (int i = 0; i < 4; i++) {
            const float ci = (i == 0) ? c0 : (i == 1) ? c1 : (i == 2) ? c2 : c3;
            const float si = (i == 0) ? s0 : (i == 1) ? s1 : (i == 2) ? s2 : s3;
            const float ua = ci * sA, ub = ci * sB;
            const float uc = -si * tA, ud = -si * tB;
            umin = fminf(umin, fminf(ua, ub) + fminf(uc, ud));
            umax = fmaxf(umax, fmaxf(ua, ub) + fmaxf(uc, ud));
            const float va = si * sA, vb = si * sB;
            const float vc = ci * tA, vd = ci * tB;
            vmin = fminf(vmin, fminf(va, vb) + fminf(vc, vd));
            vmax = fmaxf(vmax, fmaxf(va, vb) + fmaxf(vc, vd));
        }
        umin += 255.5f; umax += 255.5f; vmin += 255.5f; vmax += 255.5f;

        int u0 = max((int)floorf(umin) - 1, -2);
        u0 = ((u0 + 2) & ~1) - 2;                      // 16B-align (2-cell) DMA cols
        const int uend = min((int)floorf(umax) + 2, 513);
        const int v0   = max((int)floorf(vmin) - 1, -2);
        const int vend = min((int)floorf(vmax) + 1, 512);
        if (uend < u0 || vend < v0) continue;          // block-uniform

        // Per-thread sample offsets (swizzled) + pre-folded fp16 weights.
        // Zero-pad clamp (ciu,civ)->[-2,512] FIRST (cval=0 via padded zeros);
        // containment for act-true samples: span<=50 -> row<=49<52, col<=50<62;
        // edge cases (u0=-2 / umax>=512 -> u0>=465 -> ku<=47) verified.
        // Safety clamps only bind for act-false (m=0) samples.
        int    offs0[4], offs1[4];
        half2v w0a[4], w1a[4];
        {
            const float uA = fmaf(c_my, sA, buv), uB = fmaf(c_my, sB, buv);
            const float vA = fmaf(s_my, sA, bvv), vB = fmaf(s_my, sB, bvv);
            const float ulo = fminf(uA, uB), uhi = fmaxf(uA, uB);
            const float vlo = fminf(vA, vB), vhi = fmaxf(vA, vB);
            const bool act = (uhi > -1.0f) && (ulo < 512.0f) &&
                             (vhi > -1.0f) && (vlo < 512.0f);
            const float m = act ? 1.0f : 0.0f;
            #pragma unroll
            for (int ks = 0; ks < 4; ks++) {
                const float s = sA + (float)(ks * 8 + kp);
                const float u = fmaf(c_my, s, buv);
                const float v = fmaf(s_my, s, bvv);
                const float fu = floorf(u), fv = floorf(v);
                const float wu = u - fu, wv = v - fv;
                const float a0 = (1.0f - wu) * m, a1 = wu * m;
                const float b0 = 1.0f - wv,      b1 = wv;
                w0a[ks] = pkrtz(a0 * b0, a0 * b1);
                w1a[ks] = pkrtz(a1 * b0, a1 * b1);
                const int ciu = min(max((int)fu, -2), 512);   // zero-pad clamp
                const int civ = min(max((int)fv, -2), 512);
                const int row = min(max(civ - v0, 0), ROWS - 1);
                const int ku  = min(max(ciu - u0, 0), STC - 2);
                const int x   = XRC(row);
                offs0[ks] = row * STC + (ku ^ x);
                offs1[ks] = row * STC + ((ku + 1) ^ x);
            }
        }

        const int u0p2 = u0 + 2;   // even -> 16B-aligned global segments
        const int v0p2 = v0 + 2;

        // 4 z-pair windows, double-buffered, per-wave counted vmcnt, raw barriers.
        DMA_WINDOW(0, 0);
        // zp 0
        DMA_WINDOW(1, 1);
        WAIT_PREV();
        __builtin_amdgcn_s_barrier();
        GATHER(0, 0);
        __builtin_amdgcn_s_barrier();
        // zp 1
        DMA_WINDOW(2, 0);
        WAIT_PREV();
        __builtin_amdgcn_s_barrier();
        GATHER(1, 1);
        __builtin_amdgcn_s_barrier();
        // zp 2
        DMA_WINDOW(3, 1);
        WAIT_PREV();
        __builtin_amdgcn_s_barrier();
        GATHER(2, 0);
        __builtin_amdgcn_s_barrier();
        // zp 3
        asm volatile("s_waitcnt vmcnt(0)" ::: "memory");
        __builtin_amdgcn_s_barrier();
        GATHER(3, 1);
        __builtin_amdgcn_s_barrier();
    }

    // Reduce the 8 s-phases; lane kp writes z = kp.
    #pragma unroll
    for (int zz = 0; zz < N_Z; zz++) {
        float a = acc[zz];
        a += __shfl_xor(a, 1);
        a += __shfl_xor(a, 2);
        a += __shfl_xor(a, 4);
        acc[zz] = a;
    }
    float val = acc[0];
    #pragma unroll
    for (int zz = 1; zz < N_Z; zz++)
        if (kp == zz) val = acc[zz];
    const int det = dg * DG + deth * 8 + tl;
    out[((size_t)(kp * N_VIEW + view)) * N_DET + det] = val;
}

// ---------------- fallback (Round-5 kernel, no ws needed) ----------------
#define FDG 64
#define FSC 32
#define FNC (N_S / FSC)
#define FROWS 76
#define FSTR  81

__global__ __launch_bounds__(256) void proj_fallback(const float* __restrict__ vol,
                                                     float* __restrict__ out) {
    __shared__ float sm[FROWS * FSTR];
    const int bid  = blockIdx.x;
    const int view = bid >> 3;
    const int dg   = bid & 7;
    const int tid  = threadIdx.x;
    const int lane = tid & 63;
    const int wvid = tid >> 6;
    const int kp   = lane & 3;
    const int tl   = lane >> 2;
    const int det  = dg * FDG + wvid * 16 + tl;

    const float theta = (float)view * (float)(M_PI / 360.0);
    float si, c;
    sincosf(theta, &si, &c);
    const float t  = (float)det - 255.5f;
    const float bu = fmaf(-si, t, 255.5f);
    const float bv = fmaf( c,  t, 255.5f);

    float lo = -1e30f, hi = 1e30f;
    if (fabsf(c) > 1e-7f) {
        float a = (-1.0f - bu) / c, b = (512.0f - bu) / c;
        lo = fmaxf(lo, fminf(a, b)); hi = fminf(hi, fmaxf(a, b));
    } else if (bu <= -1.0f || bu >= 512.0f) { lo = 1e30f; hi = -1e30f; }
    if (fabsf(si) > 1e-7f) {
        float a = (-1.0f - bv) / si, b = (512.0f - bv) / si;
        lo = fmaxf(lo, fminf(a, b)); hi = fminf(hi, fmaxf(a, b));
    } else if (bv <= -1.0f || bv >= 512.0f) { lo = 1e30f; hi = -1e30f; }
    int klo = 0, khi = -1;
    if (hi >= lo) {
        klo = max(0, (int)floorf(lo + 255.5f) - 1);
        khi = min(N_S - 1, (int)ceilf(hi + 255.5f) + 1);
    }
    const float tA = (float)(dg * FDG) - 255.5f;
    const float tB = tA + (float)(FDG - 1);

    float acc[N_Z];
    #pragma unroll
    for (int z = 0; z < N_Z; z++) acc[z] = 0.0f;

    for (int ck = 0; ck < FNC; ++ck) {
        const int kbase = ck * FSC;
        const float sA = -255.5f + (float)kbase;
        const float sB = sA + (float)(FSC - 1);
        const float buA = fmaf(-si, tA, 255.5f), buB = fmaf(-si, tB, 255.5f);
        const float bvA = fmaf( c,  tA, 255.5f), bvB = fmaf( c,  tB, 255.5f);
        const float u00 = fmaf(c, sA, buA), u01 = fmaf(c, sB, buA);
        const float u10 = fmaf(c, sA, buB), u11 = fmaf(c, sB, buB);
        const float v00 = fmaf(si, sA, bvA), v01 = fmaf(si, sB, bvA);
        const float v10 = fmaf(si, sA, bvB), v11 = fmaf(si, sB, bvB);
        const float umin = fminf(fminf(u00, u01), fminf(u10, u11));
        const float umax = fmaxf(fmaxf(u00, u01), fmaxf(u10, u11));
        const float vmin = fminf(fminf(v00, v01), fminf(v10, v11));
        const float vmax = fmaxf(fmaxf(v00, v01), fmaxf(v10, v11));
        const int u0c = (int)floorf(umin) - 1;
        const int v0c = (int)floorf(vmin) - 1;
        int WU = (int)floorf(umax) - u0c + 2;
        int WV = (int)floorf(vmax) - v0c + 2;
        WU = min(WU, FSTR - 1); WV = min(WV, FROWS);
        if (u0c >= N_IMG || v0c >= N_IMG || u0c + WU <= 0 || v0c + WV <= 0) continue;
        const bool active = (klo <= kbase + FSC - 1) && (khi >= kbase);
        int offs[8]; float wus[8], wvs[8];
        if (active) {
            #pragma unroll
            for (int j = 0; j < 8; j++) {
                const int k = kbase + j * 4 + kp;
                const float s = -255.5f + (float)k;
                const float u = fmaf(c, s, bu), v = fmaf(si, s, bv);
                const float fu = floorf(u), fv = floorf(v);
                wus[j] = u - fu; wvs[j] = v - fv;
                offs[j] = ((int)fv - v0c) * FSTR + ((int)fu - u0c);
            }
        }
        const int cnt = __syncthreads_count(active ? 1 : 0);
        if (cnt == 0) continue;
        #pragma unroll
        for (int z = 0; z < N_Z; ++z) {
            const float* __restrict__ img = vol + (size_t)z * SLICE;
            for (int j = wvid; j < WV; j += 4) {
                const int r = v0c + j;
                const bool rok = (unsigned)r < (unsigned)N_IMG;
                float* dstrow = &sm[j * FSTR];
                if (lane < WU) {
                    const int cc = u0c + lane;
                    float vl = 0.0f;
                    if (rok && (unsigned)cc < (unsigned)N_IMG) vl = img[r * N_IMG + cc];
                    dstrow[lane] = vl;
                }
                if (lane < WU - 64) {
                    const int cc = u0c + 64 + lane;
                    float vl = 0.0f;
                    if (rok && (unsigned)cc < (unsigned)N_IMG) vl = img[r * N_IMG + cc];
                    dstrow[64 + lane] = vl;
                }
            }
            __syncthreads();
            if (active) {
                #pragma unroll
                for (int j = 0; j < 8; j++) {
                    const int o = offs[j];
                    const float a00 = sm[o], a01 = sm[o + 1];
                    const float a10 = sm[o + FSTR], a11 = sm[o + FSTR + 1];
                    const float wu = wus[j], wv2 = wvs[j];
                    const float top = fmaf(wu, a01 - a00, a00);
                    const float bot = fmaf(wu, a11 - a10, a10);
                    acc[z] = fmaf(wv2, bot - top, acc[z] + top);
                }
            }
            __syncthreads();
        }
    }
    #pragma unroll
    for (int z = 0; z < N_Z; z++) {
        acc[z] += __shfl_xor(acc[z], 1);
        acc[z] += __shfl_xor(acc[z], 2);
    }
    #pragma unroll
    for (int j = 0; j < 2; j++) {
        const int zt = kp * 2 + j;
        float val = 0.0f;
        #pragma unroll
        for (int zz = 0; zz < N_Z; zz++)
            if (zz == zt) val = acc[zz];
        out[((size_t)(zt * N_VIEW + view)) * N_DET + det] = val;
    }
}

extern "C" void kernel_launch(void* const* d_in, const int* in_sizes, int n_in,
                              void* d_out, int out_size, void* d_ws, size_t ws_size,
                              hipStream_t stream) {
    const float* vol = (const float*)d_in[0];
    float* out = (float*)d_out;
    (void)in_sizes; (void)n_in; (void)out_size;

    // +4KB slack: row-clamped swizzled DMA tails can overrun the last slice by <1KB.
    const size_t need = (size_t)4 * PV_ZSTRIDE * sizeof(uint2) + 4096;  // ~8.5 MB
    if (ws_size >= need) {
        uint2* pv = (uint2*)d_ws;
        pad_kernel<<<dim3(4 * PV_ROWS), dim3(256), 0, stream>>>(vol, pv);
        proj_kernel<<<dim3((N_VIEW / NV) * (N_DET / DG)), dim3(512), 0, stream>>>(pv, out);
    } else {
        proj_fallback<<<dim3(N_VIEW * 8), dim3(256), 0, stream>>>(vol, out);
    }
}

// Round 18
// 508.957 us; speedup vs baseline: 2.5572x; 2.5572x over previous
//
#include <hip/hip_runtime.h>
#include <hip/hip_fp16.h>
#include <math.h>

#define N_IMG  512
#define N_Z    8
#define N_VIEW 360
#define N_DET  512
#define N_S    512
#define SLICE  (N_IMG * N_IMG)

// Padded fp16 row-pair x z-pair volume in ws (8B cells):
//   PV2[zp][r][c].x = half2( P_{2zp}  (r-2, c-2), P_{2zp}  (r-1, c-2) )
//   PV2[zp][r][c].y = half2( P_{2zp+1}(r-2, c-2), P_{2zp+1}(r-1, c-2) )
// P = vol zero-padded. r in [0,514] covers row civ in [-2,512]; c covers ciu in [-2,513].
#define PV_ROWS    515
#define PV_PITCH   516
#define PV_ZSTRIDE (PV_ROWS * PV_PITCH)   // uint2 cells
#define NV 4          // views per block
#define DG 16         // detectors per block (512thr: window sharing via 2 det-halves)
#define SC 32         // s samples per chunk
#define NCHUNK (N_S / SC)
#define STC  64       // cells per LDS row (power of 2 -> XOR swizzle legal)
#define ROWS 52       // window rows (exact-union span proven <= 50)
#define BUFC (ROWS * STC)   // 3328 cells = 26 slots x 128
#define NSLOT 26      // 16B-seg slots per window (52 rows x 32 segs / 64 lanes)
#define NDMA 4        // max dma16 per thread per window
// Swizzle: LDS cell (r, k) holds pv col u0p2 + (k ^ XRC(r)). DMA source is
// pre-swizzled (XRC multiple of 4 cells -> 16B (2-cell) segments contiguous &
// aligned); reads use k = ku ^ XRC(row). Rule-21 compliant.
#define XRC(r) (((r) & 7) << 2)

typedef _Float16 half2v __attribute__((ext_vector_type(2)));

__device__ __forceinline__ half2v pkrtz(float a, float b) {
    return __builtin_bit_cast(half2v, __builtin_amdgcn_cvt_pkrtz(a, b));
}

__device__ __forceinline__ void dma16(const unsigned* g, unsigned* l) {
    // async global->LDS, 16B/lane; LDS dest = wave-uniform base + lane*16
    __builtin_amdgcn_global_load_lds((const __attribute__((address_space(1))) unsigned*)g,
                                     (__attribute__((address_space(3))) unsigned*)l,
                                     16, 0, 0);
}

__global__ __launch_bounds__(256) void pad_kernel(const float* __restrict__ vol,
                                                  uint2* __restrict__ pv) {
    const int zr = blockIdx.x;                  // 0 .. 4*PV_ROWS-1
    const int zp = zr / PV_ROWS;
    const int r  = zr - zp * PV_ROWS;
    const float* __restrict__ i0 = vol + (size_t)(2 * zp) * SLICE;
    const float* __restrict__ i1 = i0 + SLICE;
    uint2* __restrict__ dst = pv + (size_t)zp * PV_ZSTRIDE + (size_t)r * PV_PITCH;
    const int y0 = r - 2, y1 = r - 1;
    const bool y0ok = (unsigned)y0 < (unsigned)N_IMG;
    const bool y1ok = (unsigned)y1 < (unsigned)N_IMG;
    for (int c = threadIdx.x; c < PV_PITCH; c += 256) {
        const int x = c - 2;
        const bool xok = (unsigned)x < (unsigned)N_IMG;
        const float e0 = (y0ok && xok) ? i0[y0 * N_IMG + x] : 0.0f;
        const float e1 = (y1ok && xok) ? i0[y1 * N_IMG + x] : 0.0f;
        const float o0 = (y0ok && xok) ? i1[y0 * N_IMG + x] : 0.0f;
        const float o1 = (y1ok && xok) ? i1[y1 * N_IMG + x] : 0.0f;
        __half2 he; he.x = __float2half(e0); he.y = __float2half(e1);
        __half2 ho; ho.x = __float2half(o0); ho.y = __float2half(o1);
        uint2 cell;
        cell.x = *reinterpret_cast<unsigned*>(&he);
        cell.y = *reinterpret_cast<unsigned*>(&ho);
        dst[c] = cell;
    }
}

// Stage one zp window (52 rows x 32 segs = 26 slots). Slot predicate is
// wave-uniform (no partial slots: 26*64 = 1664 segs exactly).
#define DMA_WINDOW(ZP, B)                                                     \
    {                                                                         \
        const uint2* __restrict__ pvz = pv + (size_t)(ZP) * PV_ZSTRIDE;       \
        _Pragma("unroll")                                                     \
        for (int i = 0; i < NDMA; i++) {                                      \
            if (wvid * NDMA + i < NSLOT) {                                    \
                const int rowg = min(v0p2 + dmarow[i], PV_ROWS - 1);          \
                dma16((const unsigned*)(pvz + (size_t)rowg * PV_PITCH         \
                                        + (u0p2 + dmascol[i])),               \
                      (unsigned*)&sm2[B][(wvid * NDMA + i) * 128]);           \
            }                                                                 \
        }                                                                     \
    }

// Per-wave counted wait: window N-1 complete iff outstanding <= own issue
// count for window N ({4,4,4,4,4,4,2,0} per wave) — wave-uniform branch.
#define WAIT_PREV()                                                           \
    {                                                                         \
        if (wvid < 6)       asm volatile("s_waitcnt vmcnt(4)" ::: "memory");  \
        else if (wvid == 6) asm volatile("s_waitcnt vmcnt(2)" ::: "memory");  \
        else                asm volatile("s_waitcnt vmcnt(0)" ::: "memory");  \
    }

// One sample: 2x ds_read_b64 serve the bilinear for BOTH z of the pair.
#define GATHER(ZP, B)                                                         \
    {                                                                         \
        _Pragma("unroll")                                                     \
        for (int ks = 0; ks < 4; ks++) {                                      \
            const uint2 q0 = sm2[B][offs0[ks]];                               \
            const uint2 q1 = sm2[B][offs1[ks]];                               \
            const half2v w0 = w0a[ks], w1 = w1a[ks];                          \
            acc[2*(ZP)]   = __builtin_amdgcn_fdot2(                           \
                __builtin_bit_cast(half2v, q1.x), w1,                         \
                __builtin_amdgcn_fdot2(__builtin_bit_cast(half2v, q0.x),      \
                                       w0, acc[2*(ZP)], false),               \
                false);                                                       \
            acc[2*(ZP)+1] = __builtin_amdgcn_fdot2(                           \
                __builtin_bit_cast(half2v, q1.y), w1,                         \
                __builtin_amdgcn_fdot2(__builtin_bit_cast(half2v, q0.y),      \
                                       w0, acc[2*(ZP)+1], false),             \
                false);                                                       \
        }                                                                     \
    }

// Block: 512 threads = 8 waves = 4 views x 2 det-halves; 16 dets; all 8 z.
// Window 52x64 cells -> 53.2KB dbuf -> LDS caps residency at 3 blocks/CU
// (24 waves, 75%). launch_bounds(512,2): LOOSE VGPR bound (cap 128) — R17's
// (512,6) capped the allocator at 40 VGPR and spilled 5GB/dispatch to
// scratch (R6/R11/R17 lesson: let LDS set residency, never the VGPR cap).
__global__ __launch_bounds__(512, 2) void proj_kernel(const uint2* __restrict__ pv,
                                                      float* __restrict__ out) {
    __shared__ __align__(16) uint2 sm2[2][BUFC];

    const int g     = blockIdx.x >> 5;         // view group 0..89
    const int dg    = blockIdx.x & 31;         // det group 0..31
    const int tid   = threadIdx.x;
    const int wvid  = tid >> 6;                // wave 0..7
    const int viewt = wvid >> 1;               // wave -> view
    const int deth  = wvid & 1;                // det half 0/1
    const int lane  = tid & 63;
    const int kp    = lane & 7;                // s-phase (also the output z)
    const int tl    = lane >> 3;               // det-lane 0..7
    const int view  = g * NV + viewt;

    // Per-thread DMA geometry: seg -> (row, pre-swizzled source col).
    int dmarow[NDMA], dmascol[NDMA];
    #pragma unroll
    for (int i = 0; i < NDMA; i++) {
        const int seg = (wvid * NDMA + i) * 64 + lane;   // 0..2047 (1664 used)
        const int r   = seg >> 5;                        // 32 segs/row
        dmarow[i]  = r;
        dmascol[i] = ((seg & 31) * 2) ^ XRC(r);          // 2 cells per 16B seg
    }

    const float KTH = (float)(M_PI / 360.0);
    float c0, s0, c1, s1, c2, s2, c3, s3;
    sincosf((float)(g * 4 + 0) * KTH, &s0, &c0);
    sincosf((float)(g * 4 + 1) * KTH, &s1, &c1);
    sincosf((float)(g * 4 + 2) * KTH, &s2, &c2);
    sincosf((float)(g * 4 + 3) * KTH, &s3, &c3);
    const float c_my = (viewt == 0) ? c0 : (viewt == 1) ? c1 : (viewt == 2) ? c2 : c3;
    const float s_my = (viewt == 0) ? s0 : (viewt == 1) ? s1 : (viewt == 2) ? s2 : s3;

    const float t_base = (float)(dg * DG) - 255.5f;
    const float tt  = t_base + (float)(deth * 8 + tl);
    const float buv = fmaf(-s_my, tt, 255.5f);     // u = c*s + buv
    const float bvv = fmaf( c_my, tt, 255.5f);     // v = si*s + bvv

    float acc[N_Z];
    #pragma unroll
    for (int zz = 0; zz < N_Z; zz++) acc[zz] = 0.0f;

    for (int ck = 0; ck < NCHUNK; ++ck) {
        const float sA = (float)(ck * SC) - 255.5f;
        const float sB = sA + (float)(SC - 1);
        const float tA = t_base, tB = t_base + (float)(DG - 1);

        // Union bbox over the 4 views (block-uniform, separable corner min/max).
        float umin = 1e30f, umax = -1e30f, vmin = 1e30f, vmax = -1e30f;
        #pragma unroll
        for (int i = 0; i < 4; i++) {
            const float ci = (i == 0) ? c0 : (i == 1) ? c1 : (i == 2) ? c2 : c3;
            const float si = (i == 0) ? s0 : (i == 1) ? s1 : (i == 2) ? s2 : s3;
            const float ua = ci * sA, ub = ci * sB;
            const float uc = -si * tA, ud = -si * tB;
            umin = fminf(umin, fminf(ua, ub) + fminf(uc, ud));
            umax = fmaxf(umax, fmaxf(ua, ub) + fmaxf(uc, ud));
            const float va = si * sA, vb = si * sB;
            const float vc = ci * tA, vd = ci * tB;
            vmin = fminf(vmin, fminf(va, vb) + fminf(vc, vd));
            vmax = fmaxf(vmax, fmaxf(va, vb) + fmaxf(vc, vd));
        }
        umin += 255.5f; umax += 255.5f; vmin += 255.5f; vmax += 255.5f;

        int u0 = max((int)floorf(umin) - 1, -2);
        u0 = ((u0 + 2) & ~1) - 2;                      // 16B-align (2-cell) DMA cols
        const int uend = min((int)floorf(umax) + 2, 513);
        const int v0   = max((int)floorf(vmin) - 1, -2);
        const int vend = min((int)floorf(vmax) + 1, 512);
        if (uend < u0 || vend < v0) continue;          // block-uniform

        // Per-thread sample offsets (swizzled) + pre-folded fp16 weights.
        // Zero-pad clamp (ciu,civ)->[-2,512] FIRST (cval=0 via padded zeros);
        // containment for act-true samples: span<=50 -> row<=49<52, col<=50<62;
        // edge cases (u0=-2 / umax>=512 -> u0>=465 -> ku<=47) verified.
        // Safety clamps only bind for act-false (m=0) samples.
        int    offs0[4], offs1[4];
        half2v w0a[4], w1a[4];
        {
            const float uA = fmaf(c_my, sA, buv), uB = fmaf(c_my, sB, buv);
            const float vA = fmaf(s_my, sA, bvv), vB = fmaf(s_my, sB, bvv);
            const float ulo = fminf(uA, uB), uhi = fmaxf(uA, uB);
            const float vlo = fminf(vA, vB), vhi = fmaxf(vA, vB);
            const bool act = (uhi > -1.0f) && (ulo < 512.0f) &&
                             (vhi > -1.0f) && (vlo < 512.0f);
            const float m = act ? 1.0f : 0.0f;
            #pragma unroll
            for (int ks = 0; ks < 4; ks++) {
                const float s = sA + (float)(ks * 8 + kp);
                const float u = fmaf(c_my, s, buv);
                const float v = fmaf(s_my, s, bvv);
                const float fu = floorf(u), fv = floorf(v);
                const float wu = u - fu, wv = v - fv;
                const float a0 = (1.0f - wu) * m, a1 = wu * m;
                const float b0 = 1.0f - wv,      b1 = wv;
                w0a[ks] = pkrtz(a0 * b0, a0 * b1);
                w1a[ks] = pkrtz(a1 * b0, a1 * b1);
                const int ciu = min(max((int)fu, -2), 512);   // zero-pad clamp
                const int civ = min(max((int)fv, -2), 512);
                const int row = min(max(civ - v0, 0), ROWS - 1);
                const int ku  = min(max(ciu - u0, 0), STC - 2);
                const int x   = XRC(row);
                offs0[ks] = row * STC + (ku ^ x);
                offs1[ks] = row * STC + ((ku + 1) ^ x);
            }
        }

        const int u0p2 = u0 + 2;   // even -> 16B-aligned global segments
        const int v0p2 = v0 + 2;

        // 4 z-pair windows, double-buffered, per-wave counted vmcnt, raw barriers.
        DMA_WINDOW(0, 0);
        // zp 0
        DMA_WINDOW(1, 1);
        WAIT_PREV();
        __builtin_amdgcn_s_barrier();
        GATHER(0, 0);
        __builtin_amdgcn_s_barrier();
        // zp 1
        DMA_WINDOW(2, 0);
        WAIT_PREV();
        __builtin_amdgcn_s_barrier();
        GATHER(1, 1);
        __builtin_amdgcn_s_barrier();
        // zp 2
        DMA_WINDOW(3, 1);
        WAIT_PREV();
        __builtin_amdgcn_s_barrier();
        GATHER(2, 0);
        __builtin_amdgcn_s_barrier();
        // zp 3
        asm volatile("s_waitcnt vmcnt(0)" ::: "memory");
        __builtin_amdgcn_s_barrier();
        GATHER(3, 1);
        __builtin_amdgcn_s_barrier();
    }

    // Reduce the 8 s-phases; lane kp writes z = kp.
    #pragma unroll
    for (int zz = 0; zz < N_Z; zz++) {
        float a = acc[zz];
        a += __shfl_xor(a, 1);
        a += __shfl_xor(a, 2);
        a += __shfl_xor(a, 4);
        acc[zz] = a;
    }
    float val = acc[0];
    #pragma unroll
    for (int zz = 1; zz < N_Z; zz++)
        if (kp == zz) val = acc[zz];
    const int det = dg * DG + deth * 8 + tl;
    out[((size_t)(kp * N_VIEW + view)) * N_DET + det] = val;
}

// ---------------- fallback (Round-5 kernel, no ws needed) ----------------
#define FDG 64
#define FSC 32
#define FNC (N_S / FSC)
#define FROWS 76
#define FSTR  81

__global__ __launch_bounds__(256) void proj_fallback(const float* __restrict__ vol,
                                                     float* __restrict__ out) {
    __shared__ float sm[FROWS * FSTR];
    const int bid  = blockIdx.x;
    const int view = bid >> 3;
    const int dg   = bid & 7;
    const int tid  = threadIdx.x;
    const int lane = tid & 63;
    const int wvid = tid >> 6;
    const int kp   = lane & 3;
    const int tl   = lane >> 2;
    const int det  = dg * FDG + wvid * 16 + tl;

    const float theta = (float)view * (float)(M_PI / 360.0);
    float si, c;
    sincosf(theta, &si, &c);
    const float t  = (float)det - 255.5f;
    const float bu = fmaf(-si, t, 255.5f);
    const float bv = fmaf( c,  t, 255.5f);

    float lo = -1e30f, hi = 1e30f;
    if (fabsf(c) > 1e-7f) {
        float a = (-1.0f - bu) / c, b = (512.0f - bu) / c;
        lo = fmaxf(lo, fminf(a, b)); hi = fminf(hi, fmaxf(a, b));
    } else if (bu <= -1.0f || bu >= 512.0f) { lo = 1e30f; hi = -1e30f; }
    if (fabsf(si) > 1e-7f) {
        float a = (-1.0f - bv) / si, b = (512.0f - bv) / si;
        lo = fmaxf(lo, fminf(a, b)); hi = fminf(hi, fmaxf(a, b));
    } else if (bv <= -1.0f || bv >= 512.0f) { lo = 1e30f; hi = -1e30f; }
    int klo = 0, khi = -1;
    if (hi >= lo) {
        klo = max(0, (int)floorf(lo + 255.5f) - 1);
        khi = min(N_S - 1, (int)ceilf(hi + 255.5f) + 1);
    }
    const float tA = (float)(dg * FDG) - 255.5f;
    const float tB = tA + (float)(FDG - 1);

    float acc[N_Z];
    #pragma unroll
    for (int z = 0; z < N_Z; z++) acc[z] = 0.0f;

    for (int ck = 0; ck < FNC; ++ck) {
        const int kbase = ck * FSC;
        const float sA = -255.5f + (float)kbase;
        const float sB = sA + (float)(FSC - 1);
        const float buA = fmaf(-si, tA, 255.5f), buB = fmaf(-si, tB, 255.5f);
        const float bvA = fmaf( c,  tA, 255.5f), bvB = fmaf( c,  tB, 255.5f);
        const float u00 = fmaf(c, sA, buA), u01 = fmaf(c, sB, buA);
        const float u10 = fmaf(c, sA, buB), u11 = fmaf(c, sB, buB);
        const float v00 = fmaf(si, sA, bvA), v01 = fmaf(si, sB, bvA);
        const float v10 = fmaf(si, sA, bvB), v11 = fmaf(si, sB, bvB);
        const float umin = fminf(fminf(u00, u01), fminf(u10, u11));
        const float umax = fmaxf(fmaxf(u00, u01), fmaxf(u10, u11));
        const float vmin = fminf(fminf(v00, v01), fminf(v10, v11));
        const float vmax = fmaxf(fmaxf(v00, v01), fmaxf(v10, v11));
        const int u0c = (int)floorf(umin) - 1;
        const int v0c = (int)floorf(vmin) - 1;
        int WU = (int)floorf(umax) - u0c + 2;
        int WV = (int)floorf(vmax) - v0c + 2;
        WU = min(WU, FSTR - 1); WV = min(WV, FROWS);
        if (u0c >= N_IMG || v0c >= N_IMG || u0c + WU <= 0 || v0c + WV <= 0) continue;
        const bool active = (klo <= kbase + FSC - 1) && (khi >= kbase);
        int offs[8]; float wus[8], wvs[8];
        if (active) {
            #pragma unroll
            for (int j = 0; j < 8; j++) {
                const int k = kbase + j * 4 + kp;
                const float s = -255.5f + (float)k;
                const float u = fmaf(c, s, bu), v = fmaf(si, s, bv);
                const float fu = floorf(u), fv = floorf(v);
                wus[j] = u - fu; wvs[j] = v - fv;
                offs[j] = ((int)fv - v0c) * FSTR + ((int)fu - u0c);
            }
        }
        const int cnt = __syncthreads_count(active ? 1 : 0);
        if (cnt == 0) continue;
        #pragma unroll
        for (int z = 0; z < N_Z; ++z) {
            const float* __restrict__ img = vol + (size_t)z * SLICE;
            for (int j = wvid; j < WV; j += 4) {
                const int r = v0c + j;
                const bool rok = (unsigned)r < (unsigned)N_IMG;
                float* dstrow = &sm[j * FSTR];
                if (lane < WU) {
                    const int cc = u0c + lane;
                    float vl = 0.0f;
                    if (rok && (unsigned)cc < (unsigned)N_IMG) vl = img[r * N_IMG + cc];
                    dstrow[lane] = vl;
                }
                if (lane < WU - 64) {
                    const int cc = u0c + 64 + lane;
                    float vl = 0.0f;
                    if (rok && (unsigned)cc < (unsigned)N_IMG) vl = img[r * N_IMG + cc];
                    dstrow[64 + lane] = vl;
                }
            }
            __syncthreads();
            if (active) {
                #pragma unroll
                for (int j = 0; j < 8; j++) {
                    const int o = offs[j];
                    const float a00 = sm[o], a01 = sm[o + 1];
                    const float a10 = sm[o + FSTR], a11 = sm[o + FSTR + 1];
                    const float wu = wus[j], wv2 = wvs[j];
                    const float top = fmaf(wu, a01 - a00, a00);
                    const float bot = fmaf(wu, a11 - a10, a10);
                    acc[z] = fmaf(wv2, bot - top, acc[z] + top);
                }
            }
            __syncthreads();
        }
    }
    #pragma unroll
    for (int z = 0; z < N_Z; z++) {
        acc[z] += __shfl_xor(acc[z], 1);
        acc[z] += __shfl_xor(acc[z], 2);
    }
    #pragma unroll
    for (int j = 0; j < 2; j++) {
        const int zt = kp * 2 + j;
        float val = 0.0f;
        #pragma unroll
        for (int zz = 0; zz < N_Z; zz++)
            if (zz == zt) val = acc[zz];
        out[((size_t)(zt * N_VIEW + view)) * N_DET + det] = val;
    }
}

extern "C" void kernel_launch(void* const* d_in, const int* in_sizes, int n_in,
                              void* d_out, int out_size, void* d_ws, size_t ws_size,
                              hipStream_t stream) {
    const float* vol = (const float*)d_in[0];
    float* out = (float*)d_out;
    (void)in_sizes; (void)n_in; (void)out_size;

    // +4KB slack: row-clamped swizzled DMA tails can overrun the last slice by <1KB.
    const size_t need = (size_t)4 * PV_ZSTRIDE * sizeof(uint2) + 4096;  // ~8.5 MB
    if (ws_size >= need) {
        uint2* pv = (uint2*)d_ws;
        pad_kernel<<<dim3(4 * PV_ROWS), dim3(256), 0, stream>>>(vol, pv);
        proj_kernel<<<dim3((N_VIEW / NV) * (N_DET / DG)), dim3(512), 0, stream>>>(pv, out);
    } else {
        proj_fallback<<<dim3(N_VIEW * 8), dim3(256), 0, stream>>>(vol, out);
    }
}

// Round 19
// 251.699 us; speedup vs baseline: 5.1709x; 2.0221x over previous
//
#include <hip/hip_runtime.h>
#include <hip/hip_fp16.h>
#include <math.h>

#define N_IMG  512
#define N_Z    8
#define N_VIEW 360
#define N_DET  512
#define N_S    512
#define SLICE  (N_IMG * N_IMG)

// Padded fp16 row-pair x z-pair volume in ws (8B cells):
//   PV2[zp][r][c].x = half2( P_{2zp}  (r-2, c-2), P_{2zp}  (r-1, c-2) )
//   PV2[zp][r][c].y = half2( P_{2zp+1}(r-2, c-2), P_{2zp+1}(r-1, c-2) )
// P = vol zero-padded. r in [0,514] covers row civ in [-2,512]; c covers ciu in [-2,513].
#define PV_ROWS    515
#define PV_PITCH   516
#define PV_ZSTRIDE (PV_ROWS * PV_PITCH)   // uint2 cells
#define NV 4          // views per block
#define DG 32         // detectors per block — measured optimum (R14/R18: DG=16 loses on staging economics)
#define ND 2          // dets per thread (DG / 2 det-halves / 8 det-lanes)
#define SC 32         // s samples per chunk
#define NCHUNK (N_S / SC)
#define STC  64       // cells per LDS row (power of 2 -> XOR swizzle legal)
#define ROWS 60       // window rows (union span proven <= 58); 64 staged (clamped)
#define BUFC 4096     // cells per buffer = 64 rows x 64 cells, all DMA-written
#define NDMA 4        // dma16 per thread per window (2048 segs, 512 threads)
// Swizzle: LDS cell (r, k) holds pv col u0p2 + (k ^ XRC(r)). DMA source is
// pre-swizzled (XRC multiple of 4 cells -> 16B (2-cell) segments contiguous &
// aligned); reads use k = ku ^ XRC(row). Rule-21 compliant.
#define XRC(r) (((r) & 7) << 2)

typedef _Float16 half2v __attribute__((ext_vector_type(2)));

__device__ __forceinline__ half2v pkrtz(float a, float b) {
    return __builtin_bit_cast(half2v, __builtin_amdgcn_cvt_pkrtz(a, b));
}

__device__ __forceinline__ void dma16(const unsigned* g, unsigned* l) {
    // async global->LDS, 16B/lane; LDS dest = wave-uniform base + lane*16
    __builtin_amdgcn_global_load_lds((const __attribute__((address_space(1))) unsigned*)g,
                                     (__attribute__((address_space(3))) unsigned*)l,
                                     16, 0, 0);
}

__global__ __launch_bounds__(256) void pad_kernel(const float* __restrict__ vol,
                                                  uint2* __restrict__ pv) {
    const int zr = blockIdx.x;                  // 0 .. 4*PV_ROWS-1
    const int zp = zr / PV_ROWS;
    const int r  = zr - zp * PV_ROWS;
    const float* __restrict__ i0 = vol + (size_t)(2 * zp) * SLICE;
    const float* __restrict__ i1 = i0 + SLICE;
    uint2* __restrict__ dst = pv + (size_t)zp * PV_ZSTRIDE + (size_t)r * PV_PITCH;
    const int y0 = r - 2, y1 = r - 1;
    const bool y0ok = (unsigned)y0 < (unsigned)N_IMG;
    const bool y1ok = (unsigned)y1 < (unsigned)N_IMG;
    for (int c = threadIdx.x; c < PV_PITCH; c += 256) {
        const int x = c - 2;
        const bool xok = (unsigned)x < (unsigned)N_IMG;
        const float e0 = (y0ok && xok) ? i0[y0 * N_IMG + x] : 0.0f;
        const float e1 = (y1ok && xok) ? i0[y1 * N_IMG + x] : 0.0f;
        const float o0 = (y0ok && xok) ? i1[y0 * N_IMG + x] : 0.0f;
        const float o1 = (y1ok && xok) ? i1[y1 * N_IMG + x] : 0.0f;
        __half2 he; he.x = __float2half(e0); he.y = __float2half(e1);
        __half2 ho; ho.x = __float2half(o0); ho.y = __float2half(o1);
        uint2 cell;
        cell.x = *reinterpret_cast<unsigned*>(&he);
        cell.y = *reinterpret_cast<unsigned*>(&ho);
        dst[c] = cell;
    }
}

// Stage one zp window (64 rows x 32 segs, pre-swizzled source cols).
#define DMA_WINDOW(ZP, B)                                                     \
    {                                                                         \
        const uint2* __restrict__ pvz = pv + (size_t)(ZP) * PV_ZSTRIDE;       \
        _Pragma("unroll")                                                     \
        for (int i = 0; i < NDMA; i++) {                                      \
            const int rowg = min(v0p2 + dmarow[i], PV_ROWS - 1);              \
            dma16((const unsigned*)(pvz + (size_t)rowg * PV_PITCH             \
                                    + (u0p2 + dmascol[i])),                   \
                  (unsigned*)&sm2[B][(wvid * NDMA + i) * 128]);               \
        }                                                                     \
    }

// One sample: 2x ds_read_b64 serve the bilinear for BOTH z of the pair.
#define GATHER(ZP, B)                                                         \
    {                                                                         \
        _Pragma("unroll")                                                     \
        for (int dd = 0; dd < ND; dd++) {                                     \
            _Pragma("unroll")                                                 \
            for (int ks = 0; ks < 4; ks++) {                                  \
                const uint2 q0 = sm2[B][offs0[dd][ks]];                       \
                const uint2 q1 = sm2[B][offs1[dd][ks]];                       \
                const half2v w0 = w0a[dd][ks], w1 = w1a[dd][ks];              \
                acc[dd][2*(ZP)]   = __builtin_amdgcn_fdot2(                   \
                    __builtin_bit_cast(half2v, q1.x), w1,                     \
                    __builtin_amdgcn_fdot2(__builtin_bit_cast(half2v, q0.x),  \
                                           w0, acc[dd][2*(ZP)], false),       \
                    false);                                                   \
                acc[dd][2*(ZP)+1] = __builtin_amdgcn_fdot2(                   \
                    __builtin_bit_cast(half2v, q1.y), w1,                     \
                    __builtin_amdgcn_fdot2(__builtin_bit_cast(half2v, q0.y),  \
                                           w0, acc[dd][2*(ZP)+1], false),     \
                    false);                                                   \
            }                                                                 \
        }                                                                     \
    }

// Block: 512 threads = 8 waves = 4 views x 2 det-halves; 32 dets; all 8 z.
// R15 champion geometry (254us). launch_bounds(512,2): loose VGPR bound —
// VGPR must stay <= 64 (wave-slot boundary, m69); R17's tight bound spilled.
__global__ __launch_bounds__(512, 2) void proj_kernel(const uint2* __restrict__ pv,
                                                      float* __restrict__ out) {
    __shared__ __align__(16) uint2 sm2[2][BUFC];

    const int g     = blockIdx.x >> 4;         // view group 0..89
    const int dg    = blockIdx.x & 15;         // det group 0..15
    const int tid   = threadIdx.x;
    const int wvid  = tid >> 6;                // wave 0..7
    const int viewt = wvid & 3;                // wave -> view
    const int deth  = wvid >> 2;               // det half 0/1
    const int lane  = tid & 63;
    const int kp    = lane & 7;                // s-phase (also the output z)
    const int tl    = lane >> 3;               // det-lane 0..7
    const int view  = g * NV + viewt;

    // Per-thread DMA geometry: seg -> (row, pre-swizzled source col).
    int dmarow[NDMA], dmascol[NDMA];
    #pragma unroll
    for (int i = 0; i < NDMA; i++) {
        const int seg = (wvid * NDMA + i) * 64 + lane;   // 0..2047
        const int r   = seg >> 5;                        // 32 segs/row
        dmarow[i]  = r;
        dmascol[i] = ((seg & 31) * 2) ^ XRC(r);          // 2 cells per 16B seg
    }

    const float KTH = (float)(M_PI / 360.0);
    float c0, s0, c1, s1, c2, s2, c3, s3;
    sincosf((float)(g * 4 + 0) * KTH, &s0, &c0);
    sincosf((float)(g * 4 + 1) * KTH, &s1, &c1);
    sincosf((float)(g * 4 + 2) * KTH, &s2, &c2);
    sincosf((float)(g * 4 + 3) * KTH, &s3, &c3);
    const float c_my = (viewt == 0) ? c0 : (viewt == 1) ? c1 : (viewt == 2) ? c2 : c3;
    const float s_my = (viewt == 0) ? s0 : (viewt == 1) ? s1 : (viewt == 2) ? s2 : s3;

    const float t_base = (float)(dg * DG) - 255.5f;
    float buv[ND], bvv[ND];
    #pragma unroll
    for (int dd = 0; dd < ND; dd++) {
        const float tt = t_base + (float)(deth * 16 + dd * 8 + tl);
        buv[dd] = fmaf(-s_my, tt, 255.5f);     // u = c*s + buv
        bvv[dd] = fmaf( c_my, tt, 255.5f);     // v = si*s + bvv
    }

    float acc[ND][N_Z];
    #pragma unroll
    for (int dd = 0; dd < ND; dd++)
        #pragma unroll
        for (int zz = 0; zz < N_Z; zz++) acc[dd][zz] = 0.0f;

    for (int ck = 0; ck < NCHUNK; ++ck) {
        const float sA = (float)(ck * SC) - 255.5f;
        const float sB = sA + (float)(SC - 1);
        const float tA = t_base, tB = t_base + (float)(DG - 1);

        // Union bbox over the 4 views (block-uniform, separable corner min/max).
        float umin = 1e30f, umax = -1e30f, vmin = 1e30f, vmax = -1e30f;
        #pragma unroll
        for (int i = 0; i < 4; i++) {
            const float ci = (i == 0) ? c0 : (i == 1) ? c1 : (i == 2) ? c2 : c3;
            const float si = (i == 0) ? s0 : (i == 1) ? s1 : (i == 2) ? s2 : s3;
            const float ua = ci * sA, ub = ci * sB;
            const float uc = -si * tA, ud = -si * tB;
            umin = fminf(umin, fminf(ua, ub) + fminf(uc, ud));
            umax = fmaxf(umax, fmaxf(ua, ub) + fmaxf(uc, ud));
            const float va = si * sA, vb = si * sB;
            const float vc = ci * tA, vd = ci * tB;
            vmin = fminf(vmin, fminf(va, vb) + fminf(vc, vd));
            vmax = fmaxf(vmax, fmaxf(va, vb) + fmaxf(vc, vd));
        }
        umin += 255.5f; umax += 255.5f; vmin += 255.5f; vmax += 255.5f;

        int u0 = max((int)floorf(umin) - 1, -2);
        u0 = ((u0 + 2) & ~1) - 2;                      // 16B-align (2-cell) DMA cols
        const int uend = min((int)floorf(umax) + 2, 513);
        const int v0   = max((int)floorf(vmin) - 1, -2);
        const int vend = min((int)floorf(vmax) + 1, 512);
        if (uend < u0 || vend < v0) continue;          // block-uniform

        // Per-thread sample offsets (swizzled) + pre-folded fp16 weights.
        // Zero-pad clamp (ciu,civ)->[-2,512] FIRST (cval=0 via padded zeros);
        // containment for act-true samples proven (R13). Safety clamps after.
        int    offs0[ND][4], offs1[ND][4];
        half2v w0a[ND][4], w1a[ND][4];
        #pragma unroll
        for (int dd = 0; dd < ND; dd++) {
            const float uA = fmaf(c_my, sA, buv[dd]), uB = fmaf(c_my, sB, buv[dd]);
            const float vA = fmaf(s_my, sA, bvv[dd]), vB = fmaf(s_my, sB, bvv[dd]);
            const float ulo = fminf(uA, uB), uhi = fmaxf(uA, uB);
            const float vlo = fminf(vA, vB), vhi = fmaxf(vA, vB);
            const bool act = (uhi > -1.0f) && (ulo < 512.0f) &&
                             (vhi > -1.0f) && (vlo < 512.0f);
            const float m = act ? 1.0f : 0.0f;
            #pragma unroll
            for (int ks = 0; ks < 4; ks++) {
                const float s = sA + (float)(ks * 8 + kp);
                const float u = fmaf(c_my, s, buv[dd]);
                const float v = fmaf(s_my, s, bvv[dd]);
                const float fu = floorf(u), fv = floorf(v);
                const float wu = u - fu, wv = v - fv;
                const float a0 = (1.0f - wu) * m, a1 = wu * m;
                const float b0 = 1.0f - wv,      b1 = wv;
                w0a[dd][ks] = pkrtz(a0 * b0, a0 * b1);
                w1a[dd][ks] = pkrtz(a1 * b0, a1 * b1);
                const int ciu = min(max((int)fu, -2), 512);   // zero-pad clamp
                const int civ = min(max((int)fv, -2), 512);
                const int row = min(max(civ - v0, 0), ROWS - 1);
                const int ku  = min(max(ciu - u0, 0), STC - 2);
                const int x   = XRC(row);
                offs0[dd][ks] = row * STC + (ku ^ x);
                offs1[dd][ks] = row * STC + ((ku + 1) ^ x);
            }
        }

        const int u0p2 = u0 + 2;   // even -> 16B-aligned global segments
        const int v0p2 = v0 + 2;

        // 4 z-pair windows, double-buffered, counted vmcnt(NDMA), raw barriers.
        DMA_WINDOW(0, 0);
        // zp 0
        DMA_WINDOW(1, 1);
        asm volatile("s_waitcnt vmcnt(4)" ::: "memory");
        __builtin_amdgcn_s_barrier();
        GATHER(0, 0);
        __builtin_amdgcn_s_barrier();
        // zp 1
        DMA_WINDOW(2, 0);
        asm volatile("s_waitcnt vmcnt(4)" ::: "memory");
        __builtin_amdgcn_s_barrier();
        GATHER(1, 1);
        __builtin_amdgcn_s_barrier();
        // zp 2
        DMA_WINDOW(3, 1);
        asm volatile("s_waitcnt vmcnt(4)" ::: "memory");
        __builtin_amdgcn_s_barrier();
        GATHER(2, 0);
        __builtin_amdgcn_s_barrier();
        // zp 3
        asm volatile("s_waitcnt vmcnt(0)" ::: "memory");
        __builtin_amdgcn_s_barrier();
        GATHER(3, 1);
        __builtin_amdgcn_s_barrier();
    }

    // Reduce the 8 s-phases; lane kp writes z = kp.
    #pragma unroll
    for (int dd = 0; dd < ND; dd++) {
        #pragma unroll
        for (int zz = 0; zz < N_Z; zz++) {
            float a = acc[dd][zz];
            a += __shfl_xor(a, 1);
            a += __shfl_xor(a, 2);
            a += __shfl_xor(a, 4);
            acc[dd][zz] = a;
        }
        float val = acc[dd][0];
        #pragma unroll
        for (int zz = 1; zz < N_Z; zz++)
            if (kp == zz) val = acc[dd][zz];
        const int det = dg * DG + deth * 16 + dd * 8 + tl;
        out[((size_t)(kp * N_VIEW + view)) * N_DET + det] = val;
    }
}

// ---------------- fallback (Round-5 kernel, no ws needed) ----------------
#define FDG 64
#define FSC 32
#define FNC (N_S / FSC)
#define FROWS 76
#define FSTR  81

__global__ __launch_bounds__(256) void proj_fallback(const float* __restrict__ vol,
                                                     float* __restrict__ out) {
    __shared__ float sm[FROWS * FSTR];
    const int bid  = blockIdx.x;
    const int view = bid >> 3;
    const int dg   = bid & 7;
    const int tid  = threadIdx.x;
    const int lane = tid & 63;
    const int wvid = tid >> 6;
    const int kp   = lane & 3;
    const int tl   = lane >> 2;
    const int det  = dg * FDG + wvid * 16 + tl;

    const float theta = (float)view * (float)(M_PI / 360.0);
    float si, c;
    sincosf(theta, &si, &c);
    const float t  = (float)det - 255.5f;
    const float bu = fmaf(-si, t, 255.5f);
    const float bv = fmaf( c,  t, 255.5f);

    float lo = -1e30f, hi = 1e30f;
    if (fabsf(c) > 1e-7f) {
        float a = (-1.0f - bu) / c, b = (512.0f - bu) / c;
        lo = fmaxf(lo, fminf(a, b)); hi = fminf(hi, fmaxf(a, b));
    } else if (bu <= -1.0f || bu >= 512.0f) { lo = 1e30f; hi = -1e30f; }
    if (fabsf(si) > 1e-7f) {
        float a = (-1.0f - bv) / si, b = (512.0f - bv) / si;
        lo = fmaxf(lo, fminf(a, b)); hi = fminf(hi, fmaxf(a, b));
    } else if (bv <= -1.0f || bv >= 512.0f) { lo = 1e30f; hi = -1e30f; }
    int klo = 0, khi = -1;
    if (hi >= lo) {
        klo = max(0, (int)floorf(lo + 255.5f) - 1);
        khi = min(N_S - 1, (int)ceilf(hi + 255.5f) + 1);
    }
    const float tA = (float)(dg * FDG) - 255.5f;
    const float tB = tA + (float)(FDG - 1);

    float acc[N_Z];
    #pragma unroll
    for (int z = 0; z < N_Z; z++) acc[z] = 0.0f;

    for (int ck = 0; ck < FNC; ++ck) {
        const int kbase = ck * FSC;
        const float sA = -255.5f + (float)kbase;
        const float sB = sA + (float)(FSC - 1);
        const float buA = fmaf(-si, tA, 255.5f), buB = fmaf(-si, tB, 255.5f);
        const float bvA = fmaf( c,  tA, 255.5f), bvB = fmaf( c,  tB, 255.5f);
        const float u00 = fmaf(c, sA, buA), u01 = fmaf(c, sB, buA);
        const float u10 = fmaf(c, sA, buB), u11 = fmaf(c, sB, buB);
        const float v00 = fmaf(si, sA, bvA), v01 = fmaf(si, sB, bvA);
        const float v10 = fmaf(si, sA, bvB), v11 = fmaf(si, sB, bvB);
        const float umin = fminf(fminf(u00, u01), fminf(u10, u11));
        const float umax = fmaxf(fmaxf(u00, u01), fmaxf(u10, u11));
        const float vmin = fminf(fminf(v00, v01), fminf(v10, v11));
        const float vmax = fmaxf(fmaxf(v00, v01), fmaxf(v10, v11));
        const int u0c = (int)floorf(umin) - 1;
        const int v0c = (int)floorf(vmin) - 1;
        int WU = (int)floorf(umax) - u0c + 2;
        int WV = (int)floorf(vmax) - v0c + 2;
        WU = min(WU, FSTR - 1); WV = min(WV, FROWS);
        if (u0c >= N_IMG || v0c >= N_IMG || u0c + WU <= 0 || v0c + WV <= 0) continue;
        const bool active = (klo <= kbase + FSC - 1) && (khi >= kbase);
        int offs[8]; float wus[8], wvs[8];
        if (active) {
            #pragma unroll
            for (int j = 0; j < 8; j++) {
                const int k = kbase + j * 4 + kp;
                const float s = -255.5f + (float)k;
                const float u = fmaf(c, s, bu), v = fmaf(si, s, bv);
                const float fu = floorf(u), fv = floorf(v);
                wus[j] = u - fu; wvs[j] = v - fv;
                offs[j] = ((int)fv - v0c) * FSTR + ((int)fu - u0c);
            }
        }
        const int cnt = __syncthreads_count(active ? 1 : 0);
        if (cnt == 0) continue;
        #pragma unroll
        for (int z = 0; z < N_Z; ++z) {
            const float* __restrict__ img = vol + (size_t)z * SLICE;
            for (int j = wvid; j < WV; j += 4) {
                const int r = v0c + j;
                const bool rok = (unsigned)r < (unsigned)N_IMG;
                float* dstrow = &sm[j * FSTR];
                if (lane < WU) {
                    const int cc = u0c + lane;
                    float vl = 0.0f;
                    if (rok && (unsigned)cc < (unsigned)N_IMG) vl = img[r * N_IMG + cc];
                    dstrow[lane] = vl;
                }
                if (lane < WU - 64) {
                    const int cc = u0c + 64 + lane;
                    float vl = 0.0f;
                    if (rok && (unsigned)cc < (unsigned)N_IMG) vl = img[r * N_IMG + cc];
                    dstrow[64 + lane] = vl;
                }
            }
            __syncthreads();
            if (active) {
                #pragma unroll
                for (int j = 0; j < 8; j++) {
                    const int o = offs[j];
                    const float a00 = sm[o], a01 = sm[o + 1];
                    const float a10 = sm[o + FSTR], a11 = sm[o + FSTR + 1];
                    const float wu = wus[j], wv2 = wvs[j];
                    const float top = fmaf(wu, a01 - a00, a00);
                    const float bot = fmaf(wu, a11 - a10, a10);
                    acc[z] = fmaf(wv2, bot - top, acc[z] + top);
                }
            }
            __syncthreads();
        }
    }
    #pragma unroll
    for (int z = 0; z < N_Z; z++) {
        acc[z] += __shfl_xor(acc[z], 1);
        acc[z] += __shfl_xor(acc[z], 2);
    }
    #pragma unroll
    for (int j = 0; j < 2; j++) {
        const int zt = kp * 2 + j;
        float val = 0.0f;
        #pragma unroll
        for (int zz = 0; zz < N_Z; zz++)
            if (zz == zt) val = acc[zz];
        out[((size_t)(zt * N_VIEW + view)) * N_DET + det] = val;
    }
}

extern "C" void kernel_launch(void* const* d_in, const int* in_sizes, int n_in,
                              void* d_out, int out_size, void* d_ws, size_t ws_size,
                              hipStream_t stream) {
    const float* vol = (const float*)d_in[0];
    float* out = (float*)d_out;
    (void)in_sizes; (void)n_in; (void)out_size;

    // +4KB slack: row-clamped swizzled DMA tails can overrun the last slice by <1KB.
    const size_t need = (size_t)4 * PV_ZSTRIDE * sizeof(uint2) + 4096;  // ~8.5 MB
    if (ws_size >= need) {
        uint2* pv = (uint2*)d_ws;
        pad_kernel<<<dim3(4 * PV_ROWS), dim3(256), 0, stream>>>(vol, pv);
        proj_kernel<<<dim3((N_VIEW / NV) * (N_DET / DG)), dim3(512), 0, stream>>>(pv, out);
    } else {
        proj_fallback<<<dim3(N_VIEW * 8), dim3(256), 0, stream>>>(vol, out);
    }
}